// Round 2
// baseline (1967.646 us; speedup 1.0000x reference)
//
#include <hip/hip_runtime.h>
#include <math.h>

#define BETA_C   0.99f
#define TOL_C    1e-4f
#define MAXIT_C  1000
#define EPS_C    1e-3f
#define BN       65536
#define NN       32
#define HFD      25
#define HVD      128
#define KVD      8

// softplus = jax.nn.softplus = logaddexp(x,0) = max(x,0)+log1p(exp(-|x|))
__device__ __forceinline__ float sp_(float x) {
    return fmaxf(x, 0.f) + log1pf(expf(-fabsf(x)));
}
// d softplus / dx = sigmoid
__device__ __forceinline__ float sig_(float x) {
    return 1.f / (1.f + expf(-x));
}

// V(fx * g) with n2 = sum(fx^2).  TAN => also dV/dg (forward-mode dual).
// 128-wide hidden processed in 2 chunks of 64 to bound live accumulators.
template <bool TAN>
__device__ __forceinline__ void veval(
    const float* __restrict__ fx, float g, float n2,
    const float* __restrict__ vW1, const float* __restrict__ vb1,
    const float* __restrict__ vW2, const float* __restrict__ vb2,
    const float* __restrict__ vW3, const float* __restrict__ vb3,
    const float* __restrict__ h0g, float& Vout, float& dVout)
{
    float out[KVD], dout[KVD];
#pragma unroll
    for (int c = 0; c < KVD; ++c) { out[c] = vb3[c]; dout[c] = 0.f; }

#pragma unroll 1
    for (int ch = 0; ch < 2; ++ch) {
        float acc[64], dacc[64];
#pragma unroll
        for (int j = 0; j < 64; ++j) { acc[j] = 0.f; dacc[j] = 0.f; }

#pragma unroll 1
        for (int k = 0; k < HVD; ++k) {
            // u_k = fx . vW1[:,k]   (first layer, gamma-invariant direction)
            float u0 = 0.f, u1 = 0.f, u2 = 0.f, u3 = 0.f;
#pragma unroll
            for (int i = 0; i < NN; i += 4) {
                u0 = fmaf(fx[i + 0], vW1[(i + 0) * HVD + k], u0);
                u1 = fmaf(fx[i + 1], vW1[(i + 1) * HVD + k], u1);
                u2 = fmaf(fx[i + 2], vW1[(i + 2) * HVD + k], u2);
                u3 = fmaf(fx[i + 3], vW1[(i + 3) * HVD + k], u3);
            }
            float u = (u0 + u1) + (u2 + u3);
            float pre = fmaf(g, u, vb1[k]);
            float h1 = sp_(pre);
            float dh1 = TAN ? sig_(pre) * u : 0.f;
            const float* w2r = vW2 + k * HVD + ch * 64;
#pragma unroll
            for (int j = 0; j < 64; ++j) {
                float w = w2r[j];
                acc[j] = fmaf(h1, w, acc[j]);
                if (TAN) dacc[j] = fmaf(dh1, w, dacc[j]);
            }
        }
#pragma unroll
        for (int j = 0; j < 64; ++j) {
            int jj = ch * 64 + j;
            float pre2 = acc[j] + vb2[jj];
            float h2 = sp_(pre2);
            float dh2 = TAN ? sig_(pre2) * dacc[j] : 0.f;
            const float* w3r = vW3 + jj * KVD;
#pragma unroll
            for (int c = 0; c < KVD; ++c) {
                float w = w3r[c];
                out[c] = fmaf(h2, w, out[c]);
                if (TAN) dout[c] = fmaf(dh2, w, dout[c]);
            }
        }
    }
    float vv = 0.f, dv = 0.f;
#pragma unroll
    for (int c = 0; c < KVD; ++c) {
        float d = out[c] - h0g[c];
        vv = fmaf(d, d, vv);
        if (TAN) dv = fmaf(d, dout[c], dv);
    }
    vv += EPS_C * (g * g) * n2;
    Vout = vv;
    if (TAN) dVout = 2.f * dv + 2.f * EPS_C * g * n2;
}

// ---- h0 = V-MLP(0) : weight-only, one tiny block --------------------------
__global__ __launch_bounds__(128) void k_h0(
    const float* __restrict__ vb1, const float* __restrict__ vW2,
    const float* __restrict__ vb2, const float* __restrict__ vW3,
    const float* __restrict__ vb3, float* __restrict__ h0g)
{
    __shared__ float h1s[HVD];
    __shared__ float h2s[HVD];
    int j = threadIdx.x;
    h1s[j] = sp_(vb1[j]);
    __syncthreads();
    float a = vb2[j];
    for (int k = 0; k < HVD; ++k) a = fmaf(h1s[k], vW2[k * HVD + j], a);
    h2s[j] = sp_(a);
    __syncthreads();
    if (j < KVD) {
        float acc = vb3[j];
        for (int k = 0; k < HVD; ++k) acc = fmaf(h2s[k], vW3[k * KVD + j], acc);
        h0g[j] = acc;
    }
}

// ---- setup: fhat, V(x)->target, V(fhatx), active-compaction ---------------
// launch_bounds(256,2): VGPR cap 256 — xr[32]+fx[32]+acc[64] (~150 live)
// must NOT spill to scratch (R1 theory: default cap 124 caused spills).
__global__ __launch_bounds__(256, 2) void k_setup(
    const float* __restrict__ x_g,
    const float* __restrict__ fW1, const float* __restrict__ fb1,
    const float* __restrict__ fW2, const float* __restrict__ fb2,
    const float* __restrict__ fW3, const float* __restrict__ fb3,
    const float* __restrict__ vW1, const float* __restrict__ vb1,
    const float* __restrict__ vW2, const float* __restrict__ vb2,
    const float* __restrict__ vW3, const float* __restrict__ vb3,
    const float* __restrict__ h0g,
    float* __restrict__ out,
    int* __restrict__ cnt, int* __restrict__ list, float* __restrict__ tgt)
{
    int s = blockIdx.x * 256 + threadIdx.x;

    float xr[NN];
    const float4* xp = (const float4*)(x_g + (size_t)s * NN);
#pragma unroll
    for (int i = 0; i < NN / 4; ++i) {
        float4 v = xp[i];
        xr[4 * i + 0] = v.x; xr[4 * i + 1] = v.y;
        xr[4 * i + 2] = v.z; xr[4 * i + 3] = v.w;
    }

    // V(x) first (only xr live), then fhat, then V(fhatx).
    float n2x = 0.f;
#pragma unroll
    for (int i = 0; i < NN; ++i) n2x = fmaf(xr[i], xr[i], n2x);
    float Vx, dd;
    veval<false>(xr, 1.f, n2x, vW1, vb1, vW2, vb2, vW3, vb3, h0g, Vx, dd);
    float target = BETA_C * Vx;

    // fhat: 32 -> softplus 25 -> softplus 25 -> 32
    float h1f[HFD];
#pragma unroll
    for (int j = 0; j < HFD; ++j) {
        float a = fb1[j];
#pragma unroll
        for (int i = 0; i < NN; ++i) a = fmaf(xr[i], fW1[i * HFD + j], a);
        h1f[j] = sp_(a);
    }
    float h2f[HFD];
#pragma unroll
    for (int j = 0; j < HFD; ++j) {
        float a = fb2[j];
#pragma unroll
        for (int i = 0; i < HFD; ++i) a = fmaf(h1f[i], fW2[i * HFD + j], a);
        h2f[j] = sp_(a);
    }
    float fx[NN];
#pragma unroll
    for (int j = 0; j < NN; ++j) {
        float a = fb3[j];
#pragma unroll
        for (int i = 0; i < HFD; ++i) a = fmaf(h2f[i], fW3[i * NN + j], a);
        fx[j] = a;
    }

    // write fhatx (final answer for non-violating samples; solver rescales rest)
    float4* op = (float4*)(out + (size_t)s * NN);
#pragma unroll
    for (int i = 0; i < NN / 4; ++i)
        op[i] = make_float4(fx[4 * i], fx[4 * i + 1], fx[4 * i + 2], fx[4 * i + 3]);

    float n2f = 0.f;
#pragma unroll
    for (int i = 0; i < NN; ++i) n2f = fmaf(fx[i], fx[i], n2f);

    float v1;
    veval<false>(fx, 1.f, n2f, vW1, vb1, vW2, vb2, vW3, vb3, h0g, v1, dd);

    bool active = (v1 - target) > 0.f;

    // block-level compaction: one atomicAdd per block
    __shared__ int wbase[4];
    __shared__ int bbase;
    unsigned long long bal = __ballot(active);
    int lane = threadIdx.x & 63, wv = threadIdx.x >> 6;
    int rank = __popcll(bal & ((1ull << lane) - 1ull));
    if (lane == 0) wbase[wv] = __popcll(bal);
    __syncthreads();
    if (threadIdx.x == 0) {
        int tot = 0;
        for (int i = 0; i < 4; ++i) { int c = wbase[i]; wbase[i] = tot; tot += c; }
        bbase = atomicAdd(cnt, tot);
    }
    __syncthreads();
    if (active) {
        int p = bbase + wbase[wv] + rank;
        list[p] = s;
        tgt[p] = target;
    }
}

// ---- solver: per-thread Newton + bisection, dual-number V ------------------
// launch_bounds(64,2): VGPR cap 256. Live state fx[32]+acc[64]+dacc[64]+
// out/dout/h0 (~190) fits; R0's default cap of 124 spilled acc/dacc to
// scratch and left VALU 86% idle at 0.9 waves/CU.
__global__ __launch_bounds__(64, 2) void k_solve(
    const float* __restrict__ vW1, const float* __restrict__ vb1,
    const float* __restrict__ vW2, const float* __restrict__ vb2,
    const float* __restrict__ vW3, const float* __restrict__ vb3,
    const float* __restrict__ h0g,
    float* __restrict__ out,
    const int* __restrict__ cnt, const int* __restrict__ list,
    const float* __restrict__ tgt)
{
    int t = blockIdx.x * 64 + threadIdx.x;
    if (t >= *cnt) return;
    int s = list[t];

    float fx[NN];
    float4* op = (float4*)(out + (size_t)s * NN);
#pragma unroll
    for (int i = 0; i < NN / 4; ++i) {
        float4 v = op[i];
        fx[4 * i + 0] = v.x; fx[4 * i + 1] = v.y;
        fx[4 * i + 2] = v.z; fx[4 * i + 3] = v.w;
    }
    float n2 = 0.f;
#pragma unroll
    for (int i = 0; i < NN; ++i) n2 = fmaf(fx[i], fx[i], n2);

    float target = tgt[t];
    float h0l[KVD];
#pragma unroll
    for (int c = 0; c < KVD; ++c) h0l[c] = h0g[c];

    float gamma = 1.f, e1 = 0.f, e2 = 1.f;
    float v_e1 = 0.f;   // V(fx*0) == 0 bitwise (mlp(0)==h0)
    float v_e2 = 0.f;   // set from first dual eval (V at gamma=1)

    int it = 0;
    while (it < MAXIT_C) {
        float vp, dv;
        veval<true>(fx, gamma, n2, vW1, vb1, vW2, vb2, vW3, vb3, h0l, vp, dv);
        if (it == 0) {
            v_e2 = vp;                 // V(fx*1)
        } else if (fabsf(vp - target) <= TOL_C) {
            break;                     // reference's post-body mask check
        }
        float newt = gamma - (vp - target) / dv;
        // in-range & finite (NaN fails both comparisons -> bisect)
        bool good = (newt >= e1) && (newt <= e2);
        if (good) {
            gamma = newt;
            ++it;
        } else {
            float a = 0.5f * (e1 + e2);
            float va, du;
            veval<false>(fx, a, n2, vW1, vb1, vW2, vb2, vW3, vb3, h0l, va, du);
            float da = va - target, d1 = v_e1 - target, d2 = v_e2 - target;
            float sa = (da > 0.f) ? 1.f : ((da < 0.f) ? -1.f : 0.f);
            float s1 = (d1 > 0.f) ? 1.f : ((d1 < 0.f) ? -1.f : 0.f);
            float s2 = (d2 > 0.f) ? 1.f : ((d2 < 0.f) ? -1.f : 0.f);
            if (sa * s1 < 0.f) { e2 = a; v_e2 = va; }
            if (sa * s2 < 0.f) { e1 = a; v_e1 = va; }
            gamma = a;
            ++it;
            if (fabsf(va - target) <= TOL_C) break;
        }
    }

#pragma unroll
    for (int i = 0; i < NN / 4; ++i)
        op[i] = make_float4(fx[4 * i + 0] * gamma, fx[4 * i + 1] * gamma,
                            fx[4 * i + 2] * gamma, fx[4 * i + 3] * gamma);
}

extern "C" void kernel_launch(void* const* d_in, const int* in_sizes, int n_in,
                              void* d_out, int out_size, void* d_ws, size_t ws_size,
                              hipStream_t stream)
{
    const float* x   = (const float*)d_in[0];
    const float* fW1 = (const float*)d_in[1];
    const float* fb1 = (const float*)d_in[2];
    const float* fW2 = (const float*)d_in[3];
    const float* fb2 = (const float*)d_in[4];
    const float* fW3 = (const float*)d_in[5];
    const float* fb3 = (const float*)d_in[6];
    const float* vW1 = (const float*)d_in[7];
    const float* vb1 = (const float*)d_in[8];
    const float* vW2 = (const float*)d_in[9];
    const float* vb2 = (const float*)d_in[10];
    const float* vW3 = (const float*)d_in[11];
    const float* vb3 = (const float*)d_in[12];
    float* out = (float*)d_out;

    char* ws = (char*)d_ws;
    int*   cnt  = (int*)ws;                                  // 4 B
    float* h0g  = (float*)(ws + 64);                         // 8 floats
    int*   list = (int*)(ws + 128);                          // BN ints
    float* tgt  = (float*)(ws + 128 + (size_t)BN * 4);       // BN floats

    hipMemsetAsync(cnt, 0, sizeof(int), stream);

    hipLaunchKernelGGL(k_h0, dim3(1), dim3(HVD), 0, stream,
                       vb1, vW2, vb2, vW3, vb3, h0g);

    hipLaunchKernelGGL(k_setup, dim3(BN / 256), dim3(256), 0, stream,
                       x, fW1, fb1, fW2, fb2, fW3, fb3,
                       vW1, vb1, vW2, vb2, vW3, vb3,
                       h0g, out, cnt, list, tgt);

    hipLaunchKernelGGL(k_solve, dim3(BN / 64), dim3(64), 0, stream,
                       vW1, vb1, vW2, vb2, vW3, vb3,
                       h0g, out, cnt, list, tgt);
}

// Round 3
// 802.595 us; speedup vs baseline: 2.4516x; 2.4516x over previous
//
#include <hip/hip_runtime.h>
#include <math.h>

#define BETA_C   0.99f
#define TOL_C    1e-4f
#define MAXIT_C  1000
#define EPS_C    1e-3f
#define BN       65536
#define NN       32
#define HFD      25
#define HVD      128
#define KVD      8
#define G        16   // lanes per cooperative group (1 sample per group)
#define GPB      16   // groups per 256-thread block

// wave-internal LDS ordering: groups live inside one wave, so a full block
// barrier is unnecessary (and illegal inside the divergent solve loop).
// threadfence_block -> s_waitcnt lgkmcnt(0); wave_barrier pins compiler order.
__device__ __forceinline__ void wsync() {
    __builtin_amdgcn_wave_barrier();
    __threadfence_block();
    __builtin_amdgcn_wave_barrier();
}

__device__ __forceinline__ float sp_(float x) {
    return fmaxf(x, 0.f) + log1pf(expf(-fabsf(x)));
}
// fused softplus + sigmoid (shares one expf)
__device__ __forceinline__ void spsig_(float x, float& sp, float& sg) {
    float t = expf(-fabsf(x));
    sp = fmaxf(x, 0.f) + log1pf(t);
    float r = 1.f / (1.f + t);
    sg = (x >= 0.f) ? r : t * r;
}

// Cooperative V(fx*g): 16 lanes, lane gl owns hidden units [gl*8, gl*8+8).
// fxrow: 32 floats in LDS (group row). h1row: 128 float2 (h1, dh1) in LDS.
// TAN => also dV/dg. All lanes return bitwise-identical V/dV (butterfly).
template <bool TAN>
__device__ __forceinline__ void gveval(
    const int gl,
    float2* __restrict__ h1row, const float* __restrict__ fxrow,
    const float g, const float n2,
    const float* __restrict__ vW1, const float* __restrict__ vb1,
    const float* __restrict__ vW2, const float* __restrict__ vb2,
    const float* __restrict__ vW3, const float* __restrict__ vb3,
    const float* __restrict__ h0g,
    float& Vout, float& dVout)
{
    const int k0 = gl * 8;
    // ---- layer 1: u_k = fx . W1[:,k] for this lane's 8 k's (coalesced rows)
    float u[8];
#pragma unroll
    for (int j = 0; j < 8; ++j) u[j] = 0.f;
#pragma unroll
    for (int i = 0; i < NN; ++i) {
        const float4 wa = *(const float4*)(vW1 + i * HVD + k0);
        const float4 wb = *(const float4*)(vW1 + i * HVD + k0 + 4);
        const float xv = fxrow[i];
        u[0] = fmaf(xv, wa.x, u[0]); u[1] = fmaf(xv, wa.y, u[1]);
        u[2] = fmaf(xv, wa.z, u[2]); u[3] = fmaf(xv, wa.w, u[3]);
        u[4] = fmaf(xv, wb.x, u[4]); u[5] = fmaf(xv, wb.y, u[5]);
        u[6] = fmaf(xv, wb.z, u[6]); u[7] = fmaf(xv, wb.w, u[7]);
    }
    {
        const float4 ba = *(const float4*)(vb1 + k0);
        const float4 bb = *(const float4*)(vb1 + k0 + 4);
        const float bv[8] = {ba.x, ba.y, ba.z, ba.w, bb.x, bb.y, bb.z, bb.w};
#pragma unroll
        for (int j = 0; j < 8; ++j) {
            const float pre = fmaf(g, u[j], bv[j]);
            if (TAN) {
                float sp, sg; spsig_(pre, sp, sg);
                h1row[k0 + j] = make_float2(sp, sg * u[j]);
            } else {
                h1row[k0 + j] = make_float2(sp_(pre), 0.f);
            }
        }
    }
    wsync();
    // ---- layer 2: acc_j = sum_k h1[k] * W2[k][j], lane's 8 j's
    float acc[8], dacc[8];
#pragma unroll
    for (int j = 0; j < 8; ++j) { acc[j] = 0.f; dacc[j] = 0.f; }
#pragma unroll 4
    for (int k = 0; k < HVD; ++k) {
        const float2 hp = h1row[k];                       // LDS broadcast
        const float4 wa = *(const float4*)(vW2 + k * HVD + k0);
        const float4 wb = *(const float4*)(vW2 + k * HVD + k0 + 4);
        acc[0] = fmaf(hp.x, wa.x, acc[0]); acc[1] = fmaf(hp.x, wa.y, acc[1]);
        acc[2] = fmaf(hp.x, wa.z, acc[2]); acc[3] = fmaf(hp.x, wa.w, acc[3]);
        acc[4] = fmaf(hp.x, wb.x, acc[4]); acc[5] = fmaf(hp.x, wb.y, acc[5]);
        acc[6] = fmaf(hp.x, wb.z, acc[6]); acc[7] = fmaf(hp.x, wb.w, acc[7]);
        if (TAN) {
            dacc[0] = fmaf(hp.y, wa.x, dacc[0]); dacc[1] = fmaf(hp.y, wa.y, dacc[1]);
            dacc[2] = fmaf(hp.y, wa.z, dacc[2]); dacc[3] = fmaf(hp.y, wa.w, dacc[3]);
            dacc[4] = fmaf(hp.y, wb.x, dacc[4]); dacc[5] = fmaf(hp.y, wb.y, dacc[5]);
            dacc[6] = fmaf(hp.y, wb.z, dacc[6]); dacc[7] = fmaf(hp.y, wb.w, dacc[7]);
        }
    }
    wsync();   // WAR: next eval's layer-1 writes must not pass these reads
    // ---- layer 3: partial out[c] over lane's 8 j's
    float o[KVD], dO[KVD];
#pragma unroll
    for (int c = 0; c < KVD; ++c) { o[c] = 0.f; dO[c] = 0.f; }
    {
        const float4 ba = *(const float4*)(vb2 + k0);
        const float4 bb = *(const float4*)(vb2 + k0 + 4);
        const float bv[8] = {ba.x, ba.y, ba.z, ba.w, bb.x, bb.y, bb.z, bb.w};
#pragma unroll
        for (int j = 0; j < 8; ++j) {
            const float pre2 = acc[j] + bv[j];
            float h2, dh2 = 0.f;
            if (TAN) { float sp, sg; spsig_(pre2, sp, sg); h2 = sp; dh2 = sg * dacc[j]; }
            else h2 = sp_(pre2);
            const float4 w3a = *(const float4*)(vW3 + (k0 + j) * KVD);
            const float4 w3b = *(const float4*)(vW3 + (k0 + j) * KVD + 4);
            o[0] = fmaf(h2, w3a.x, o[0]); o[1] = fmaf(h2, w3a.y, o[1]);
            o[2] = fmaf(h2, w3a.z, o[2]); o[3] = fmaf(h2, w3a.w, o[3]);
            o[4] = fmaf(h2, w3b.x, o[4]); o[5] = fmaf(h2, w3b.y, o[5]);
            o[6] = fmaf(h2, w3b.z, o[6]); o[7] = fmaf(h2, w3b.w, o[7]);
            if (TAN) {
                dO[0] = fmaf(dh2, w3a.x, dO[0]); dO[1] = fmaf(dh2, w3a.y, dO[1]);
                dO[2] = fmaf(dh2, w3a.z, dO[2]); dO[3] = fmaf(dh2, w3a.w, dO[3]);
                dO[4] = fmaf(dh2, w3b.x, dO[4]); dO[5] = fmaf(dh2, w3b.y, dO[5]);
                dO[6] = fmaf(dh2, w3b.z, dO[6]); dO[7] = fmaf(dh2, w3b.w, dO[7]);
            }
        }
    }
    // ---- 16-lane butterfly (masks 1,2,4,8 stay inside the group)
#pragma unroll
    for (int m = 1; m < G; m <<= 1) {
#pragma unroll
        for (int c = 0; c < KVD; ++c) {
            o[c] += __shfl_xor(o[c], m);
            if (TAN) dO[c] += __shfl_xor(dO[c], m);
        }
    }
    float vv = 0.f, dv = 0.f;
#pragma unroll
    for (int c = 0; c < KVD; ++c) {
        const float d = (o[c] + vb3[c]) - h0g[c];   // vb3/h0: uniform s_loads
        vv = fmaf(d, d, vv);
        if (TAN) dv = fmaf(d, dO[c], dv);
    }
    Vout = vv + EPS_C * g * g * n2;
    if (TAN) dVout = 2.f * dv + 2.f * EPS_C * g * n2;
}

// ---- h0 = V-MLP(0) : weight-only, one tiny block --------------------------
__global__ __launch_bounds__(128) void k_h0(
    const float* __restrict__ vb1, const float* __restrict__ vW2,
    const float* __restrict__ vb2, const float* __restrict__ vW3,
    const float* __restrict__ vb3, float* __restrict__ h0g)
{
    __shared__ float h1s[HVD];
    __shared__ float h2s[HVD];
    int j = threadIdx.x;
    h1s[j] = sp_(vb1[j]);
    __syncthreads();
    float a = vb2[j];
    for (int k = 0; k < HVD; ++k) a = fmaf(h1s[k], vW2[k * HVD + j], a);
    h2s[j] = sp_(a);
    __syncthreads();
    if (j < KVD) {
        float acc = vb3[j];
        for (int k = 0; k < HVD; ++k) acc = fmaf(h2s[k], vW3[k * KVD + j], acc);
        h0g[j] = acc;
    }
}

// ---- setup: fhat, V(x)->target, V(fhatx), active-compaction ---------------
__global__ __launch_bounds__(256, 3) void k_setup(
    const float* __restrict__ x_g,
    const float* __restrict__ fW1, const float* __restrict__ fb1,
    const float* __restrict__ fW2, const float* __restrict__ fb2,
    const float* __restrict__ fW3, const float* __restrict__ fb3,
    const float* __restrict__ vW1, const float* __restrict__ vb1,
    const float* __restrict__ vW2, const float* __restrict__ vb2,
    const float* __restrict__ vW3, const float* __restrict__ vb3,
    const float* __restrict__ h0g,
    float* __restrict__ out,
    int* __restrict__ cnt, int* __restrict__ list, float* __restrict__ tgt)
{
    __shared__ float2 h1s[GPB][HVD + 2];
    __shared__ float  fxs[GPB][NN + 2];
    __shared__ float  fh1[GPB][HFD + 1];
    __shared__ float  fh2[GPB][HFD + 1];
    __shared__ int    wcnt[4];
    __shared__ int    bbase;

    const int gi = threadIdx.x >> 4;
    const int gl = threadIdx.x & (G - 1);
    const int s  = blockIdx.x * GPB + gi;
    float2* h1row = h1s[gi];
    float*  fxrow = fxs[gi];

    // stage x into LDS (lane gl handles elements gl, gl+16)
    fxrow[gl]      = x_g[(size_t)s * NN + gl];
    fxrow[gl + 16] = x_g[(size_t)s * NN + gl + 16];
    wsync();

    float n2x = 0.f;
#pragma unroll
    for (int i = 0; i < NN; ++i) n2x = fmaf(fxrow[i], fxrow[i], n2x);
    float Vx, dd;
    gveval<false>(gl, h1row, fxrow, 1.f, n2x,
                  vW1, vb1, vW2, vb2, vW3, vb3, h0g, Vx, dd);
    const float target = BETA_C * Vx;

    // ---- fhat (lane-parallel over hidden units)
    for (int uu = gl; uu < HFD; uu += G) {
        float a = fb1[uu];
#pragma unroll
        for (int i = 0; i < NN; ++i) a = fmaf(fxrow[i], fW1[i * HFD + uu], a);
        fh1[gi][uu] = sp_(a);
    }
    wsync();
    for (int uu = gl; uu < HFD; uu += G) {
        float a = fb2[uu];
#pragma unroll
        for (int i = 0; i < HFD; ++i) a = fmaf(fh1[gi][i], fW2[i * HFD + uu], a);
        fh2[gi][uu] = sp_(a);
    }
    wsync();
    float fo0 = fb3[gl], fo1 = fb3[gl + 16];
#pragma unroll
    for (int i = 0; i < HFD; ++i) {
        const float h = fh2[gi][i];
        fo0 = fmaf(h, fW3[i * NN + gl], fo0);
        fo1 = fmaf(h, fW3[i * NN + gl + 16], fo1);
    }
    wsync();                       // all lanes done reading x before overwrite
    fxrow[gl] = fo0; fxrow[gl + 16] = fo1;
    out[(size_t)s * NN + gl]      = fo0;
    out[(size_t)s * NN + gl + 16] = fo1;
    wsync();

    float n2f = 0.f;
#pragma unroll
    for (int i = 0; i < NN; ++i) n2f = fmaf(fxrow[i], fxrow[i], n2f);
    float v1;
    gveval<false>(gl, h1row, fxrow, 1.f, n2f,
                  vW1, vb1, vW2, vb2, vW3, vb3, h0g, v1, dd);

    const bool active = (v1 - target) > 0.f;

    // compaction: one entry per active group, one atomicAdd per block
    const bool lead = active && (gl == 0);
    unsigned long long bal = __ballot(lead);
    const int lane = threadIdx.x & 63, wv = threadIdx.x >> 6;
    const int rank = __popcll(bal & ((1ull << lane) - 1ull));
    if (lane == 0) wcnt[wv] = __popcll(bal);
    __syncthreads();
    if (threadIdx.x == 0) {
        int tot = 0;
        for (int i = 0; i < 4; ++i) { int c = wcnt[i]; wcnt[i] = tot; tot += c; }
        bbase = atomicAdd(cnt, tot);
    }
    __syncthreads();
    if (lead) {
        const int p = bbase + wcnt[wv] + rank;
        list[p] = s;
        tgt[p] = target;
    }
}

// ---- solver: 16-lane group per active sample, Newton + bisection ----------
// No block barriers anywhere (groups diverge in iteration count).
__global__ __launch_bounds__(256, 3) void k_solve(
    const float* __restrict__ vW1, const float* __restrict__ vb1,
    const float* __restrict__ vW2, const float* __restrict__ vb2,
    const float* __restrict__ vW3, const float* __restrict__ vb3,
    const float* __restrict__ h0g,
    float* __restrict__ out,
    const int* __restrict__ cnt, const int* __restrict__ list,
    const float* __restrict__ tgt)
{
    __shared__ float2 h1s[GPB][HVD + 2];
    __shared__ float  fxs[GPB][NN + 2];

    const int gi = threadIdx.x >> 4;
    const int gl = threadIdx.x & (G - 1);
    const int t  = blockIdx.x * GPB + gi;
    const int n  = *cnt;
    if (t >= n) return;

    const int s = list[t];
    const float target = tgt[t];
    float2* h1row = h1s[gi];
    float*  fxrow = fxs[gi];

    fxrow[gl]      = out[(size_t)s * NN + gl];
    fxrow[gl + 16] = out[(size_t)s * NN + gl + 16];
    wsync();
    float n2 = 0.f;
#pragma unroll
    for (int i = 0; i < NN; ++i) n2 = fmaf(fxrow[i], fxrow[i], n2);

    float gamma = 1.f, e1 = 0.f, e2 = 1.f;
    float v_e1 = 0.f;   // V(fx*0) == 0 bitwise
    float v_e2 = 0.f;   // set from first dual eval (V at gamma=1)

    int it = 0;
    while (it < MAXIT_C) {
        float vp, dv;
        gveval<true>(gl, h1row, fxrow, gamma, n2,
                     vW1, vb1, vW2, vb2, vW3, vb3, h0g, vp, dv);
        if (it == 0) {
            v_e2 = vp;
        } else if (fabsf(vp - target) <= TOL_C) {
            break;
        }
        const float newt = gamma - (vp - target) / dv;
        const bool good = (newt >= e1) && (newt <= e2);   // NaN -> bisect
        if (good) {
            gamma = newt;
            ++it;
        } else {
            const float a = 0.5f * (e1 + e2);
            float va, du;
            gveval<false>(gl, h1row, fxrow, a, n2,
                          vW1, vb1, vW2, vb2, vW3, vb3, h0g, va, du);
            const float da = va - target, d1 = v_e1 - target, d2 = v_e2 - target;
            const float sa = (da > 0.f) ? 1.f : ((da < 0.f) ? -1.f : 0.f);
            const float s1 = (d1 > 0.f) ? 1.f : ((d1 < 0.f) ? -1.f : 0.f);
            const float s2 = (d2 > 0.f) ? 1.f : ((d2 < 0.f) ? -1.f : 0.f);
            if (sa * s1 < 0.f) { e2 = a; v_e2 = va; }
            if (sa * s2 < 0.f) { e1 = a; v_e1 = va; }
            gamma = a;
            ++it;
            if (fabsf(va - target) <= TOL_C) break;
        }
    }

    out[(size_t)s * NN + gl]      = fxrow[gl] * gamma;
    out[(size_t)s * NN + gl + 16] = fxrow[gl + 16] * gamma;
}

extern "C" void kernel_launch(void* const* d_in, const int* in_sizes, int n_in,
                              void* d_out, int out_size, void* d_ws, size_t ws_size,
                              hipStream_t stream)
{
    const float* x   = (const float*)d_in[0];
    const float* fW1 = (const float*)d_in[1];
    const float* fb1 = (const float*)d_in[2];
    const float* fW2 = (const float*)d_in[3];
    const float* fb2 = (const float*)d_in[4];
    const float* fW3 = (const float*)d_in[5];
    const float* fb3 = (const float*)d_in[6];
    const float* vW1 = (const float*)d_in[7];
    const float* vb1 = (const float*)d_in[8];
    const float* vW2 = (const float*)d_in[9];
    const float* vb2 = (const float*)d_in[10];
    const float* vW3 = (const float*)d_in[11];
    const float* vb3 = (const float*)d_in[12];
    float* out = (float*)d_out;

    char* ws = (char*)d_ws;
    int*   cnt  = (int*)ws;                                  // 4 B
    float* h0g  = (float*)(ws + 64);                         // 8 floats
    int*   list = (int*)(ws + 128);                          // BN ints
    float* tgt  = (float*)(ws + 128 + (size_t)BN * 4);       // BN floats

    hipMemsetAsync(cnt, 0, sizeof(int), stream);

    hipLaunchKernelGGL(k_h0, dim3(1), dim3(HVD), 0, stream,
                       vb1, vW2, vb2, vW3, vb3, h0g);

    hipLaunchKernelGGL(k_setup, dim3(BN / GPB), dim3(256), 0, stream,
                       x, fW1, fb1, fW2, fb2, fW3, fb3,
                       vW1, vb1, vW2, vb2, vW3, vb3,
                       h0g, out, cnt, list, tgt);

    hipLaunchKernelGGL(k_solve, dim3(BN / GPB), dim3(256), 0, stream,
                       vW1, vb1, vW2, vb2, vW3, vb3,
                       h0g, out, cnt, list, tgt);
}

// Round 4
// 552.821 us; speedup vs baseline: 3.5593x; 1.4518x over previous
//
#include <hip/hip_runtime.h>
#include <math.h>

#define BETA_C   0.99f
#define TOL_C    1e-4f
#define MAXIT_C  1000
#define EPS_C    1e-3f
#define BN       65536
#define NN       32
#define HFD      25
#define HVD      128
#define KVD      8
#define G        16   // lanes per cooperative group (1 sample per group)
#define GPB      16   // groups per 256-thread block

// wave-internal LDS ordering: groups live inside one wave, so no block
// barrier (illegal in the divergent solve loop anyway).
__device__ __forceinline__ void wsync() {
    __builtin_amdgcn_wave_barrier();
    __threadfence_block();
    __builtin_amdgcn_wave_barrier();
}

__device__ __forceinline__ float sp_(float x) {
    return fmaxf(x, 0.f) + log1pf(expf(-fabsf(x)));
}
// fused softplus + sigmoid (shares one expf)
__device__ __forceinline__ void spsig_(float x, float& sp, float& sg) {
    float t = expf(-fabsf(x));
    sp = fmaxf(x, 0.f) + log1pf(t);
    float r = 1.f / (1.f + t);
    sg = (x >= 0.f) ? r : t * r;
}
__device__ __forceinline__ float sgn_(float d) {
    return (d > 0.f) ? 1.f : ((d < 0.f) ? -1.f : 0.f);
}

// ---------------------------------------------------------------------------
// layer1 for TWO inputs sharing W1 loads: u_k = fx . W1[:,k], lane's 8 k's
__device__ __forceinline__ void layer1_u2(
    const int gl, const float* __restrict__ fxa, const float* __restrict__ fxb,
    const float* __restrict__ vW1, float (&ua)[8], float (&ub)[8])
{
    const int k0 = gl * 8;
#pragma unroll
    for (int j = 0; j < 8; ++j) { ua[j] = 0.f; ub[j] = 0.f; }
#pragma unroll
    for (int i = 0; i < NN; ++i) {
        const float4 wa = *(const float4*)(vW1 + i * HVD + k0);
        const float4 wb = *(const float4*)(vW1 + i * HVD + k0 + 4);
        const float xa = fxa[i], xb = fxb[i];
        ua[0] = fmaf(xa, wa.x, ua[0]); ua[1] = fmaf(xa, wa.y, ua[1]);
        ua[2] = fmaf(xa, wa.z, ua[2]); ua[3] = fmaf(xa, wa.w, ua[3]);
        ua[4] = fmaf(xa, wb.x, ua[4]); ua[5] = fmaf(xa, wb.y, ua[5]);
        ua[6] = fmaf(xa, wb.z, ua[6]); ua[7] = fmaf(xa, wb.w, ua[7]);
        ub[0] = fmaf(xb, wa.x, ub[0]); ub[1] = fmaf(xb, wa.y, ub[1]);
        ub[2] = fmaf(xb, wa.z, ub[2]); ub[3] = fmaf(xb, wa.w, ub[3]);
        ub[4] = fmaf(xb, wb.x, ub[4]); ub[5] = fmaf(xb, wb.y, ub[5]);
        ub[6] = fmaf(xb, wb.z, ub[6]); ub[7] = fmaf(xb, wb.w, ub[7]);
    }
}

// layer1 for one input
__device__ __forceinline__ void layer1_u1(
    const int gl, const float* __restrict__ fx,
    const float* __restrict__ vW1, float (&u)[8])
{
    const int k0 = gl * 8;
#pragma unroll
    for (int j = 0; j < 8; ++j) u[j] = 0.f;
#pragma unroll
    for (int i = 0; i < NN; ++i) {
        const float4 wa = *(const float4*)(vW1 + i * HVD + k0);
        const float4 wb = *(const float4*)(vW1 + i * HVD + k0 + 4);
        const float xv = fx[i];
        u[0] = fmaf(xv, wa.x, u[0]); u[1] = fmaf(xv, wa.y, u[1]);
        u[2] = fmaf(xv, wa.z, u[2]); u[3] = fmaf(xv, wa.w, u[3]);
        u[4] = fmaf(xv, wb.x, u[4]); u[5] = fmaf(xv, wb.y, u[5]);
        u[6] = fmaf(xv, wb.z, u[6]); u[7] = fmaf(xv, wb.w, u[7]);
    }
}

// ---------------------------------------------------------------------------
// batched B=2 plain eval at g=1 (k_setup): inputs via cached u; h1 rows float
__device__ __forceinline__ void veval2_plain(
    const int gl, const float (&ua)[8], const float (&ub)[8],
    float* __restrict__ h1a, float* __restrict__ h1b,
    const float n2a, const float n2b,
    const float* __restrict__ vb1, const float* __restrict__ vW2,
    const float* __restrict__ vb2, const float* __restrict__ vW3,
    const float* __restrict__ vb3, const float* __restrict__ h0g,
    float& Va, float& Vb)
{
    const int k0 = gl * 8;
    {
        const float4 b1a = *(const float4*)(vb1 + k0);
        const float4 b1b = *(const float4*)(vb1 + k0 + 4);
        const float bv[8] = {b1a.x, b1a.y, b1a.z, b1a.w, b1b.x, b1b.y, b1b.z, b1b.w};
        float4 va0, va1, vb0, vb1v;
        va0.x = sp_(ua[0] + bv[0]); va0.y = sp_(ua[1] + bv[1]);
        va0.z = sp_(ua[2] + bv[2]); va0.w = sp_(ua[3] + bv[3]);
        va1.x = sp_(ua[4] + bv[4]); va1.y = sp_(ua[5] + bv[5]);
        va1.z = sp_(ua[6] + bv[6]); va1.w = sp_(ua[7] + bv[7]);
        vb0.x = sp_(ub[0] + bv[0]); vb0.y = sp_(ub[1] + bv[1]);
        vb0.z = sp_(ub[2] + bv[2]); vb0.w = sp_(ub[3] + bv[3]);
        vb1v.x = sp_(ub[4] + bv[4]); vb1v.y = sp_(ub[5] + bv[5]);
        vb1v.z = sp_(ub[6] + bv[6]); vb1v.w = sp_(ub[7] + bv[7]);
        *(float4*)(h1a + k0) = va0; *(float4*)(h1a + k0 + 4) = va1;
        *(float4*)(h1b + k0) = vb0; *(float4*)(h1b + k0 + 4) = vb1v;
    }
    wsync();
    float aa[8], ab[8];
#pragma unroll
    for (int j = 0; j < 8; ++j) { aa[j] = 0.f; ab[j] = 0.f; }
#pragma unroll 4
    for (int k = 0; k < HVD; ++k) {
        const float ha = h1a[k], hb = h1b[k];           // LDS broadcast
        const float4 wa = *(const float4*)(vW2 + k * HVD + k0);
        const float4 wb = *(const float4*)(vW2 + k * HVD + k0 + 4);
        aa[0] = fmaf(ha, wa.x, aa[0]); aa[1] = fmaf(ha, wa.y, aa[1]);
        aa[2] = fmaf(ha, wa.z, aa[2]); aa[3] = fmaf(ha, wa.w, aa[3]);
        aa[4] = fmaf(ha, wb.x, aa[4]); aa[5] = fmaf(ha, wb.y, aa[5]);
        aa[6] = fmaf(ha, wb.z, aa[6]); aa[7] = fmaf(ha, wb.w, aa[7]);
        ab[0] = fmaf(hb, wa.x, ab[0]); ab[1] = fmaf(hb, wa.y, ab[1]);
        ab[2] = fmaf(hb, wa.z, ab[2]); ab[3] = fmaf(hb, wa.w, ab[3]);
        ab[4] = fmaf(hb, wb.x, ab[4]); ab[5] = fmaf(hb, wb.y, ab[5]);
        ab[6] = fmaf(hb, wb.z, ab[6]); ab[7] = fmaf(hb, wb.w, ab[7]);
    }
    wsync();
    float oa[KVD], ob[KVD];
#pragma unroll
    for (int c = 0; c < KVD; ++c) { oa[c] = 0.f; ob[c] = 0.f; }
    {
        const float4 b2a = *(const float4*)(vb2 + k0);
        const float4 b2b = *(const float4*)(vb2 + k0 + 4);
        const float bv[8] = {b2a.x, b2a.y, b2a.z, b2a.w, b2b.x, b2b.y, b2b.z, b2b.w};
#pragma unroll
        for (int j = 0; j < 8; ++j) {
            const float h2a = sp_(aa[j] + bv[j]);
            const float h2b = sp_(ab[j] + bv[j]);
            const float4 w3a = *(const float4*)(vW3 + (k0 + j) * KVD);
            const float4 w3b = *(const float4*)(vW3 + (k0 + j) * KVD + 4);
            oa[0] = fmaf(h2a, w3a.x, oa[0]); oa[1] = fmaf(h2a, w3a.y, oa[1]);
            oa[2] = fmaf(h2a, w3a.z, oa[2]); oa[3] = fmaf(h2a, w3a.w, oa[3]);
            oa[4] = fmaf(h2a, w3b.x, oa[4]); oa[5] = fmaf(h2a, w3b.y, oa[5]);
            oa[6] = fmaf(h2a, w3b.z, oa[6]); oa[7] = fmaf(h2a, w3b.w, oa[7]);
            ob[0] = fmaf(h2b, w3a.x, ob[0]); ob[1] = fmaf(h2b, w3a.y, ob[1]);
            ob[2] = fmaf(h2b, w3a.z, ob[2]); ob[3] = fmaf(h2b, w3a.w, ob[3]);
            ob[4] = fmaf(h2b, w3b.x, ob[4]); ob[5] = fmaf(h2b, w3b.y, ob[5]);
            ob[6] = fmaf(h2b, w3b.z, ob[6]); ob[7] = fmaf(h2b, w3b.w, ob[7]);
        }
    }
#pragma unroll
    for (int m = 1; m < G; m <<= 1) {
#pragma unroll
        for (int c = 0; c < KVD; ++c) {
            oa[c] += __shfl_xor(oa[c], m);
            ob[c] += __shfl_xor(ob[c], m);
        }
    }
    float vva = 0.f, vvb = 0.f;
#pragma unroll
    for (int c = 0; c < KVD; ++c) {
        const float da = (oa[c] + vb3[c]) - h0g[c];
        const float db = (ob[c] + vb3[c]) - h0g[c];
        vva = fmaf(da, da, vva);
        vvb = fmaf(db, db, vvb);
    }
    Va = vva + EPS_C * n2a;   // g = 1
    Vb = vvb + EPS_C * n2b;
}

// ---------------------------------------------------------------------------
// single TAN eval from cached u (k_solve): V(fx*g), dV/dg
__device__ __forceinline__ void veval1_tan(
    const int gl, const float (&u)[8], const float g,
    float2* __restrict__ h1row, const float n2,
    const float* __restrict__ vb1, const float* __restrict__ vW2,
    const float* __restrict__ vb2, const float* __restrict__ vW3,
    const float* __restrict__ vb3, const float* __restrict__ h0g,
    float& Vout, float& dVout)
{
    const int k0 = gl * 8;
    {
        const float4 b1a = *(const float4*)(vb1 + k0);
        const float4 b1b = *(const float4*)(vb1 + k0 + 4);
        const float bv[8] = {b1a.x, b1a.y, b1a.z, b1a.w, b1b.x, b1b.y, b1b.z, b1b.w};
#pragma unroll
        for (int j = 0; j < 8; ++j) {
            const float pre = fmaf(g, u[j], bv[j]);
            float sp, sg; spsig_(pre, sp, sg);
            h1row[k0 + j] = make_float2(sp, sg * u[j]);
        }
    }
    wsync();
    float acc[8], dacc[8];
#pragma unroll
    for (int j = 0; j < 8; ++j) { acc[j] = 0.f; dacc[j] = 0.f; }
#pragma unroll 4
    for (int k = 0; k < HVD; ++k) {
        const float2 hp = h1row[k];
        const float4 wa = *(const float4*)(vW2 + k * HVD + k0);
        const float4 wb = *(const float4*)(vW2 + k * HVD + k0 + 4);
        acc[0] = fmaf(hp.x, wa.x, acc[0]); acc[1] = fmaf(hp.x, wa.y, acc[1]);
        acc[2] = fmaf(hp.x, wa.z, acc[2]); acc[3] = fmaf(hp.x, wa.w, acc[3]);
        acc[4] = fmaf(hp.x, wb.x, acc[4]); acc[5] = fmaf(hp.x, wb.y, acc[5]);
        acc[6] = fmaf(hp.x, wb.z, acc[6]); acc[7] = fmaf(hp.x, wb.w, acc[7]);
        dacc[0] = fmaf(hp.y, wa.x, dacc[0]); dacc[1] = fmaf(hp.y, wa.y, dacc[1]);
        dacc[2] = fmaf(hp.y, wa.z, dacc[2]); dacc[3] = fmaf(hp.y, wa.w, dacc[3]);
        dacc[4] = fmaf(hp.y, wb.x, dacc[4]); dacc[5] = fmaf(hp.y, wb.y, dacc[5]);
        dacc[6] = fmaf(hp.y, wb.z, dacc[6]); dacc[7] = fmaf(hp.y, wb.w, dacc[7]);
    }
    wsync();
    float o[KVD], dO[KVD];
#pragma unroll
    for (int c = 0; c < KVD; ++c) { o[c] = 0.f; dO[c] = 0.f; }
    {
        const float4 b2a = *(const float4*)(vb2 + k0);
        const float4 b2b = *(const float4*)(vb2 + k0 + 4);
        const float bv[8] = {b2a.x, b2a.y, b2a.z, b2a.w, b2b.x, b2b.y, b2b.z, b2b.w};
#pragma unroll
        for (int j = 0; j < 8; ++j) {
            const float pre2 = acc[j] + bv[j];
            float h2, sg; spsig_(pre2, h2, sg);
            const float dh2 = sg * dacc[j];
            const float4 w3a = *(const float4*)(vW3 + (k0 + j) * KVD);
            const float4 w3b = *(const float4*)(vW3 + (k0 + j) * KVD + 4);
            o[0] = fmaf(h2, w3a.x, o[0]); o[1] = fmaf(h2, w3a.y, o[1]);
            o[2] = fmaf(h2, w3a.z, o[2]); o[3] = fmaf(h2, w3a.w, o[3]);
            o[4] = fmaf(h2, w3b.x, o[4]); o[5] = fmaf(h2, w3b.y, o[5]);
            o[6] = fmaf(h2, w3b.z, o[6]); o[7] = fmaf(h2, w3b.w, o[7]);
            dO[0] = fmaf(dh2, w3a.x, dO[0]); dO[1] = fmaf(dh2, w3a.y, dO[1]);
            dO[2] = fmaf(dh2, w3a.z, dO[2]); dO[3] = fmaf(dh2, w3a.w, dO[3]);
            dO[4] = fmaf(dh2, w3b.x, dO[4]); dO[5] = fmaf(dh2, w3b.y, dO[5]);
            dO[6] = fmaf(dh2, w3b.z, dO[6]); dO[7] = fmaf(dh2, w3b.w, dO[7]);
        }
    }
#pragma unroll
    for (int m = 1; m < G; m <<= 1) {
#pragma unroll
        for (int c = 0; c < KVD; ++c) {
            o[c] += __shfl_xor(o[c], m);
            dO[c] += __shfl_xor(dO[c], m);
        }
    }
    float vv = 0.f, dv = 0.f;
#pragma unroll
    for (int c = 0; c < KVD; ++c) {
        const float d = (o[c] + vb3[c]) - h0g[c];
        vv = fmaf(d, d, vv);
        dv = fmaf(d, dO[c], dv);
    }
    Vout = vv + EPS_C * g * g * n2;
    dVout = 2.f * dv + 2.f * EPS_C * g * n2;
}

// ---- h0 = V-MLP(0) : weight-only, one tiny block --------------------------
__global__ __launch_bounds__(128) void k_h0(
    const float* __restrict__ vb1, const float* __restrict__ vW2,
    const float* __restrict__ vb2, const float* __restrict__ vW3,
    const float* __restrict__ vb3, float* __restrict__ h0g)
{
    __shared__ float h1s[HVD];
    __shared__ float h2s[HVD];
    int j = threadIdx.x;
    h1s[j] = sp_(vb1[j]);
    __syncthreads();
    float a = vb2[j];
    for (int k = 0; k < HVD; ++k) a = fmaf(h1s[k], vW2[k * HVD + j], a);
    h2s[j] = sp_(a);
    __syncthreads();
    if (j < KVD) {
        float acc = vb3[j];
        for (int k = 0; k < HVD; ++k) acc = fmaf(h2s[k], vW3[k * KVD + j], acc);
        h0g[j] = acc;
    }
}

// ---- setup: fhat, then ONE batched weight pass for V(x) & V(fhatx) --------
__global__ __launch_bounds__(256, 3) void k_setup(
    const float* __restrict__ x_g,
    const float* __restrict__ fW1, const float* __restrict__ fb1,
    const float* __restrict__ fW2, const float* __restrict__ fb2,
    const float* __restrict__ fW3, const float* __restrict__ fb3,
    const float* __restrict__ vW1, const float* __restrict__ vb1,
    const float* __restrict__ vW2, const float* __restrict__ vb2,
    const float* __restrict__ vW3, const float* __restrict__ vb3,
    const float* __restrict__ h0g,
    float* __restrict__ out,
    int* __restrict__ cnt, int* __restrict__ list, float* __restrict__ tgt)
{
    __shared__ float h1s[GPB][2][HVD + 4];
    __shared__ float fxs[GPB][2][NN + 2];
    __shared__ float fh1[GPB][HFD + 1];
    __shared__ float fh2[GPB][HFD + 1];
    __shared__ int   wcnt[4];
    __shared__ int   bbase;

    const int gi = threadIdx.x >> 4;
    const int gl = threadIdx.x & (G - 1);
    const int s  = blockIdx.x * GPB + gi;
    float* xrow = fxs[gi][0];
    float* frow = fxs[gi][1];

    // stage x
    xrow[gl]      = x_g[(size_t)s * NN + gl];
    xrow[gl + 16] = x_g[(size_t)s * NN + gl + 16];
    wsync();

    // ---- fhat (lane-parallel over hidden units)
    for (int uu = gl; uu < HFD; uu += G) {
        float a = fb1[uu];
#pragma unroll
        for (int i = 0; i < NN; ++i) a = fmaf(xrow[i], fW1[i * HFD + uu], a);
        fh1[gi][uu] = sp_(a);
    }
    wsync();
    for (int uu = gl; uu < HFD; uu += G) {
        float a = fb2[uu];
#pragma unroll
        for (int i = 0; i < HFD; ++i) a = fmaf(fh1[gi][i], fW2[i * HFD + uu], a);
        fh2[gi][uu] = sp_(a);
    }
    wsync();
    float fo0 = fb3[gl], fo1 = fb3[gl + 16];
#pragma unroll
    for (int i = 0; i < HFD; ++i) {
        const float h = fh2[gi][i];
        fo0 = fmaf(h, fW3[i * NN + gl], fo0);
        fo1 = fmaf(h, fW3[i * NN + gl + 16], fo1);
    }
    frow[gl] = fo0; frow[gl + 16] = fo1;
    out[(size_t)s * NN + gl]      = fo0;
    out[(size_t)s * NN + gl + 16] = fo1;
    wsync();

    float n2x = 0.f, n2f = 0.f;
#pragma unroll
    for (int i = 0; i < NN; ++i) {
        n2x = fmaf(xrow[i], xrow[i], n2x);
        n2f = fmaf(frow[i], frow[i], n2f);
    }

    // ---- batched V eval over {x, fhatx}: one weight pass, 2x FMA density
    float ux[8], uf[8];
    layer1_u2(gl, xrow, frow, vW1, ux, uf);
    float Vx, Vf;
    veval2_plain(gl, ux, uf, h1s[gi][0], h1s[gi][1], n2x, n2f,
                 vb1, vW2, vb2, vW3, vb3, h0g, Vx, Vf);

    const float target = BETA_C * Vx;
    const bool active = (Vf - target) > 0.f;

    // compaction: one entry per active group, one atomicAdd per block
    const bool lead = active && (gl == 0);
    unsigned long long bal = __ballot(lead);
    const int lane = threadIdx.x & 63, wv = threadIdx.x >> 6;
    const int rank = __popcll(bal & ((1ull << lane) - 1ull));
    if (lane == 0) wcnt[wv] = __popcll(bal);
    __syncthreads();
    if (threadIdx.x == 0) {
        int tot = 0;
        for (int i = 0; i < 4; ++i) { int c = wcnt[i]; wcnt[i] = tot; tot += c; }
        bbase = atomicAdd(cnt, tot);
    }
    __syncthreads();
    if (lead) {
        const int p = bbase + wcnt[wv] + rank;
        list[p] = s;
        tgt[p] = target;
    }
}

// ---- solver: 16-lane group per active sample --------------------------------
// u = fx.W1 cached in regs (gamma-invariant); ONE TAN eval per iteration:
// a bisection midpoint's bracket update is deferred to the next iteration's
// eval (same V value the reference computes; same iteration count).
__global__ __launch_bounds__(256, 3) void k_solve(
    const float* __restrict__ vW1, const float* __restrict__ vb1,
    const float* __restrict__ vW2, const float* __restrict__ vb2,
    const float* __restrict__ vW3, const float* __restrict__ vb3,
    const float* __restrict__ h0g,
    float* __restrict__ out,
    const int* __restrict__ cnt, const int* __restrict__ list,
    const float* __restrict__ tgt)
{
    __shared__ float2 h1s[GPB][HVD + 2];
    __shared__ float  fxs[GPB][NN + 2];

    const int gi = threadIdx.x >> 4;
    const int gl = threadIdx.x & (G - 1);
    const int t  = blockIdx.x * GPB + gi;
    const int n  = *cnt;
    if (t >= n) return;

    const int s = list[t];
    const float target = tgt[t];
    float2* h1row = h1s[gi];
    float*  fxrow = fxs[gi];

    const float f0 = out[(size_t)s * NN + gl];
    const float f1 = out[(size_t)s * NN + gl + 16];
    fxrow[gl] = f0; fxrow[gl + 16] = f1;
    wsync();
    float n2 = 0.f;
#pragma unroll
    for (int i = 0; i < NN; ++i) n2 = fmaf(fxrow[i], fxrow[i], n2);

    float u[8];
    layer1_u1(gl, fxrow, vW1, u);

    float gamma = 1.f, e1 = 0.f, e2 = 1.f;
    float v_e1 = 0.f;       // V(fx*0) == 0 (mlp(0)==h0 to ulp; target >> ulp)
    float v_e2 = 0.f;       // set at it==0 (V at gamma=1)
    bool pend = false;      // bracket update deferred to next eval
    int it = 0;

    while (it < MAXIT_C) {
        float vp, dv;
        veval1_tan(gl, u, gamma, h1row, n2,
                   vb1, vW2, vb2, vW3, vb3, h0g, vp, dv);
        if (pend) {
            const float sa = sgn_(vp - target);
            const float s1 = sgn_(v_e1 - target);
            const float s2 = sgn_(v_e2 - target);
            if (sa * s1 < 0.f) { e2 = gamma; v_e2 = vp; }
            if (sa * s2 < 0.f) { e1 = gamma; v_e1 = vp; }
            pend = false;
        }
        if (it == 0) {
            v_e2 = vp;
        } else if (fabsf(vp - target) <= TOL_C) {
            break;
        }
        const float newt = gamma - (vp - target) / dv;
        if (newt >= e1 && newt <= e2) {       // NaN fails -> bisect
            gamma = newt;
        } else {
            gamma = 0.5f * (e1 + e2);
            pend = true;
        }
        ++it;
    }

    out[(size_t)s * NN + gl]      = f0 * gamma;
    out[(size_t)s * NN + gl + 16] = f1 * gamma;
}

extern "C" void kernel_launch(void* const* d_in, const int* in_sizes, int n_in,
                              void* d_out, int out_size, void* d_ws, size_t ws_size,
                              hipStream_t stream)
{
    const float* x   = (const float*)d_in[0];
    const float* fW1 = (const float*)d_in[1];
    const float* fb1 = (const float*)d_in[2];
    const float* fW2 = (const float*)d_in[3];
    const float* fb2 = (const float*)d_in[4];
    const float* fW3 = (const float*)d_in[5];
    const float* fb3 = (const float*)d_in[6];
    const float* vW1 = (const float*)d_in[7];
    const float* vb1 = (const float*)d_in[8];
    const float* vW2 = (const float*)d_in[9];
    const float* vb2 = (const float*)d_in[10];
    const float* vW3 = (const float*)d_in[11];
    const float* vb3 = (const float*)d_in[12];
    float* out = (float*)d_out;

    char* ws = (char*)d_ws;
    int*   cnt  = (int*)ws;                                  // 4 B
    float* h0g  = (float*)(ws + 64);                         // 8 floats
    int*   list = (int*)(ws + 128);                          // BN ints
    float* tgt  = (float*)(ws + 128 + (size_t)BN * 4);       // BN floats

    hipMemsetAsync(cnt, 0, sizeof(int), stream);

    hipLaunchKernelGGL(k_h0, dim3(1), dim3(HVD), 0, stream,
                       vb1, vW2, vb2, vW3, vb3, h0g);

    hipLaunchKernelGGL(k_setup, dim3(BN / GPB), dim3(256), 0, stream,
                       x, fW1, fb1, fW2, fb2, fW3, fb3,
                       vW1, vb1, vW2, vb2, vW3, vb3,
                       h0g, out, cnt, list, tgt);

    hipLaunchKernelGGL(k_solve, dim3(BN / GPB), dim3(256), 0, stream,
                       vW1, vb1, vW2, vb2, vW3, vb3,
                       h0g, out, cnt, list, tgt);
}